// Round 11
// baseline (93.431 us; speedup 1.0000x reference)
//
#include <hip/hip_runtime.h>

// MultiGaussSpatialConv: B=1, N=M=8192, D=3, C=16, fp32.
// out[n,c] = sum_i w_i * (sum_m e_i(n,m) yf[m,c]) / (sum_m e_i(n,m))
// e_i = exp(-d2/(2 s^2)), 1/(2 s^2) = {200, 50, 12.5} -> e0 = e2^16, e1 = e2^4.
//
// R11: q-traffic amortization. R10 (issue diet) won 21us, confirming the
// kernel is issue/throughput-bound. Remaining wall: every (n,m) pair pulls
// q[m] (16B) through the LDS/L1 return path because each lane serves one
// n-row -> 1.07 GB of broadcast traffic. Now each WAVE owns TWO 16-row
// n-tiles: q float4s and B-fragments are read once and feed both tiles
// (8 B/pair). 12 MFMAs/kt, ~110 VALU/kt for 1024 pairs. Grid (64,16),
// NCH=16 chunks; peeled last kt removes in-loop branches; A-frags built
// via shufflevector concat (no pack junk).

static constexpr int Nn = 8192;
static constexpr int Mm = 8192;
static constexpr int NCH = 16;              // m-chunks
static constexpr int NKT = 256 / NCH;       // kt per wave (16)
static constexpr float KC = 36.0673761f;    // 25 * log2(e)
static constexpr float KD = -18.0336880f;   // -12.5 * log2(e)

typedef _Float16 half8 __attribute__((ext_vector_type(8)));
typedef __fp16  fp16x2 __attribute__((ext_vector_type(2)));
typedef __fp16  fp16x4 __attribute__((ext_vector_type(4)));
typedef __fp16  fp16x8 __attribute__((ext_vector_type(8)));
typedef float  float4v __attribute__((ext_vector_type(4)));

#define MFMA_F16 __builtin_amdgcn_mfma_f32_16x16x32_f16
#define EXP2F(v) __builtin_amdgcn_exp2f(v)

// ---------------- prep: q[m] quad (constant-folded) + yf -> fp16 B-fragments
// frag idx(m,c) = (m>>5)*512 + (((m&31)>>3)*16 + c)*8 + (m&7)
__global__ __launch_bounds__(256) void mgsc_prep(
    const float* __restrict__ y, const float* __restrict__ yf,
    float4* __restrict__ q, _Float16* __restrict__ frag)
{
    const int t = blockIdx.x * 256 + threadIdx.x;   // 0 .. Mm*16-1
    const int m = t >> 4, c = t & 15;
    const int idx = ((m >> 5) << 9) + ((((m & 31) >> 3) << 4) + c) * 8 + (m & 7);
    frag[idx] = (_Float16)yf[t];                    // RNE
    if (t < Mm) {
        const float ax = y[3 * t], ay = y[3 * t + 1], az = y[3 * t + 2];
        q[t] = make_float4(KC * ax, KC * ay, KC * az,
                           KD * (ax * ax + ay * ay + az * az));
    }
}

// A-frag triple (e2, e2^4, e2^16) from 8 fp32 e2 values, packed math
struct Frags { half8 a0, a1, a2; };
__device__ __forceinline__ Frags make_frags(const float E[8]) {
    fp16x2 p[4], q1[4], q0[4];
#pragma unroll
    for (int jj = 0; jj < 4; ++jj) {
        p[jj] = __builtin_amdgcn_cvt_pkrtz(E[2 * jj], E[2 * jj + 1]);
        const fp16x2 s2 = p[jj] * p[jj];            // v_pk_mul_f16
        q1[jj] = s2 * s2;                           // e2^4
        const fp16x2 s1 = q1[jj] * q1[jj];
        q0[jj] = s1 * s1;                           // e2^16
    }
    Frags f;
    {
        const fp16x4 lo = __builtin_shufflevector(p[0], p[1], 0, 1, 2, 3);
        const fp16x4 hi = __builtin_shufflevector(p[2], p[3], 0, 1, 2, 3);
        f.a2 = __builtin_bit_cast(half8, __builtin_shufflevector(lo, hi, 0, 1, 2, 3, 4, 5, 6, 7));
    }
    {
        const fp16x4 lo = __builtin_shufflevector(q1[0], q1[1], 0, 1, 2, 3);
        const fp16x4 hi = __builtin_shufflevector(q1[2], q1[3], 0, 1, 2, 3);
        f.a1 = __builtin_bit_cast(half8, __builtin_shufflevector(lo, hi, 0, 1, 2, 3, 4, 5, 6, 7));
    }
    {
        const fp16x4 lo = __builtin_shufflevector(q0[0], q0[1], 0, 1, 2, 3);
        const fp16x4 hi = __builtin_shufflevector(q0[2], q0[3], 0, 1, 2, 3);
        f.a0 = __builtin_bit_cast(half8, __builtin_shufflevector(lo, hi, 0, 1, 2, 3, 4, 5, 6, 7));
    }
    return f;
}

// ---------------- main: grid (64, NCH); 4 waves/block; TWO n-tiles per wave
__global__ __launch_bounds__(256, 4) void mgsc_main(
    const float* __restrict__ x, const float4* __restrict__ q,
    const _Float16* __restrict__ frag, float* __restrict__ part)
{
    __shared__ float4 qS[NKT * 32];                 // 8 KB: block's q chunk

    const int tid  = threadIdx.x;
    const int wave = tid >> 6, lane = tid & 63;
    const int g    = lane >> 4, c = lane & 15;
    const int xb   = blockIdx.x, yb = blockIdx.y;
    const int n0   = (xb * 4 + wave) * 32;          // this wave's 32 n-rows
    const int rA   = n0 + c;                        // tile A row
    const int rB   = n0 + 16 + c;                   // tile B row

    // stage q chunk (shared by all 4 waves: same yb); 512 float4, 2/thread
    const float4* qsrc = q + ((size_t)yb * NKT << 5);
    qS[tid]       = qsrc[tid];
    qS[tid + 256] = qsrc[tid + 256];

    const float xxA = x[3 * rA], xyA = x[3 * rA + 1], xzA = x[3 * rA + 2];
    const float xxB = x[3 * rB], xyB = x[3 * rB + 1], xzB = x[3 * rB + 2];
    const float E2xA = EXP2F(KD * __fmaf_rn(xxA, xxA, __fmaf_rn(xyA, xyA, xzA * xzA)));
    const float E2xB = EXP2F(KD * __fmaf_rn(xxB, xxB, __fmaf_rn(xyB, xyB, xzB * xzB)));

    float4v aA0 = {0.f, 0.f, 0.f, 0.f}, aA1 = aA0, aA2 = aA0;
    float4v dA0 = aA0, dA1 = aA0, dA2 = aA0;
    float4v aB0 = aA0, aB1 = aA0, aB2 = aA0;
    float4v dB0 = aA0, dB1 = aA0, dB2 = aA0;

    const _Float16 onev = (c == 0) ? (_Float16)1.0f : (_Float16)0.0f;
    half8 bone = {onev, onev, onev, onev, onev, onev, onev, onev};

    __syncthreads();                                // q chunk ready (only barrier)

    const _Float16* fpp = frag + ((size_t)yb * NKT << 9) + (lane << 3);
    half8 Bc = *reinterpret_cast<const half8*>(fpp);

    for (int ktl = 0; ktl < NKT; ++ktl) {
        half8 Bn;
        if (ktl + 1 < NKT) {                        // prefetch next B-frag
            fpp += 512;
            Bn = *reinterpret_cast<const half8*>(fpp);
        }
        const float4* qk = &qS[(ktl << 5) + (g << 3)];
        float EA[8], EB[8];
#pragma unroll
        for (int j = 0; j < 8; ++j) {
            const float4 Q = qk[j];                 // read once, feed BOTH tiles
            const float argA = __fmaf_rn(xxA, Q.x, __fmaf_rn(xyA, Q.y, __fmaf_rn(xzA, Q.z, Q.w)));
            const float argB = __fmaf_rn(xxB, Q.x, __fmaf_rn(xyB, Q.y, __fmaf_rn(xzB, Q.z, Q.w)));
            EA[j] = E2xA * EXP2F(argA);             // e2 <= ~1
            EB[j] = E2xB * EXP2F(argB);
        }
        const Frags fA = make_frags(EA);
        const Frags fB = make_frags(EB);
        aA0 = MFMA_F16(fA.a0, Bc, aA0, 0, 0, 0);
        aA1 = MFMA_F16(fA.a1, Bc, aA1, 0, 0, 0);
        aA2 = MFMA_F16(fA.a2, Bc, aA2, 0, 0, 0);
        dA0 = MFMA_F16(fA.a0, bone, dA0, 0, 0, 0);
        dA1 = MFMA_F16(fA.a1, bone, dA1, 0, 0, 0);
        dA2 = MFMA_F16(fA.a2, bone, dA2, 0, 0, 0);
        aB0 = MFMA_F16(fB.a0, Bc, aB0, 0, 0, 0);
        aB1 = MFMA_F16(fB.a1, Bc, aB1, 0, 0, 0);
        aB2 = MFMA_F16(fB.a2, Bc, aB2, 0, 0, 0);
        dB0 = MFMA_F16(fB.a0, bone, dB0, 0, 0, 0);
        dB1 = MFMA_F16(fB.a1, bone, dB1, 0, 0, 0);
        dB2 = MFMA_F16(fB.a2, bone, dB2, 0, 0, 0);
        if (ktl + 1 < NKT) Bc = Bn;
    }

    // ---- write both tiles' partials: part[yb][n][52], plain stores
    float* pb = part + ((size_t)yb * Nn) * 52;
#pragma unroll
    for (int r = 0; r < 4; ++r) {
        const int nA = n0 + (g << 2) + r;           // C/D: col=c, row=g*4+r
        float* rowA = pb + (size_t)nA * 52;
        rowA[c]      = aA0[r];
        rowA[16 + c] = aA1[r];
        rowA[32 + c] = aA2[r];
        if (c == 0) { rowA[48] = dA0[r]; rowA[49] = dA1[r]; rowA[50] = dA2[r]; }
        const int nB = n0 + 16 + (g << 2) + r;
        float* rowB = pb + (size_t)nB * 52;
        rowB[c]      = aB0[r];
        rowB[16 + c] = aB1[r];
        rowB[32 + c] = aB2[r];
        if (c == 0) { rowB[48] = dB0[r]; rowB[49] = dB1[r]; rowB[50] = dB2[r]; }
    }
}

// ---------------- reduce: thread (n,c) sums NCH chunks, finalizes
__global__ __launch_bounds__(256) void mgsc_reduce(
    const float* __restrict__ part, float* __restrict__ out)
{
    const int t = blockIdx.x * 256 + threadIdx.x;   // 0 .. Nn*16-1
    const int n = t >> 4, c = t & 15;
    float s0 = 0.f, s1 = 0.f, s2 = 0.f, d0 = 0.f, d1 = 0.f, d2 = 0.f;
#pragma unroll
    for (int k = 0; k < NCH; ++k) {
        const float* row = part + ((size_t)k * Nn + n) * 52;
        s0 += row[c];
        s1 += row[16 + c];
        s2 += row[32 + c];
        d0 += row[48];
        d1 += row[49];
        d2 += row[50];
    }
    out[(size_t)n * 16 + c] = 0.3f * s0 / d0 + 0.3f * s1 / d1 + 0.4f * s2 / d2;
}

// ---------------- fused VALU fallback (workspace too small)
__global__ __launch_bounds__(256) void mgsc_fused(
    const float* __restrict__ x, const float* __restrict__ y,
    const float* __restrict__ yf, float* __restrict__ out)
{
    __shared__ float yS[256 * 3];
    __shared__ float yfS[256 * 16];
    const int tid = threadIdx.x;
    const int n   = blockIdx.x * 256 + tid;
    const float xx = x[3 * n], xy = x[3 * n + 1], xz = x[3 * n + 2];
    float a0[16], a1[16], a2[16];
#pragma unroll
    for (int c = 0; c < 16; ++c) { a0[c] = 0.f; a1[c] = 0.f; a2[c] = 0.f; }
    float den0 = 0.f, den1 = 0.f, den2 = 0.f;
    for (int mt = 0; mt < Mm; mt += 256) {
        const float4* ysrc = reinterpret_cast<const float4*>(y + (size_t)mt * 3);
        if (tid < 192) reinterpret_cast<float4*>(yS)[tid] = ysrc[tid];
        const float4* fsrc = reinterpret_cast<const float4*>(yf + (size_t)mt * 16);
#pragma unroll
        for (int k = 0; k < 4; ++k)
            reinterpret_cast<float4*>(yfS)[tid + 256 * k] = fsrc[tid + 256 * k];
        __syncthreads();
        for (int mm = 0; mm < 256; ++mm) {
            const float dx = xx - yS[3 * mm], dy = xy - yS[3 * mm + 1], dz = xz - yS[3 * mm + 2];
            const float d2 = dx * dx + dy * dy + dz * dz;
            const float e2 = __expf(-12.5f * d2);
            const float t = e2 * e2, e1 = t * t, u = e1 * e1, e0 = u * u;
            den0 += e0; den1 += e1; den2 += e2;
            const float4* fr = reinterpret_cast<const float4*>(yfS + mm * 16);
#pragma unroll
            for (int k = 0; k < 4; ++k) {
                const float4 f = fr[k];
                a0[4*k+0] += e0 * f.x; a0[4*k+1] += e0 * f.y; a0[4*k+2] += e0 * f.z; a0[4*k+3] += e0 * f.w;
                a1[4*k+0] += e1 * f.x; a1[4*k+1] += e1 * f.y; a1[4*k+2] += e1 * f.z; a1[4*k+3] += e1 * f.w;
                a2[4*k+0] += e2 * f.x; a2[4*k+1] += e2 * f.y; a2[4*k+2] += e2 * f.z; a2[4*k+3] += e2 * f.w;
            }
        }
        __syncthreads();
    }
    const float r0 = 0.3f / den0, r1 = 0.3f / den1, r2 = 0.4f / den2;
#pragma unroll
    for (int c = 0; c < 16; ++c)
        out[(size_t)n * 16 + c] = a0[c] * r0 + a1[c] * r1 + a2[c] * r2;
}

extern "C" void kernel_launch(void* const* d_in, const int* in_sizes, int n_in,
                              void* d_out, int out_size, void* d_ws, size_t ws_size,
                              hipStream_t stream) {
    const float* x  = (const float*)d_in[0];
    const float* y  = (const float*)d_in[1];
    const float* yf = (const float*)d_in[2];
    float* out = (float*)d_out;

    const size_t qB    = (size_t)Mm * sizeof(float4);            // 128 KB
    const size_t fragB = (size_t)Mm * 16 * sizeof(_Float16);     // 256 KB
    const size_t partB = (size_t)NCH * Nn * 52 * sizeof(float);  // 27.3 MB
    if (qB + fragB + partB > ws_size) {
        mgsc_fused<<<Nn / 256, 256, 0, stream>>>(x, y, yf, out);
        return;
    }
    float4*   q    = (float4*)d_ws;
    _Float16* frag = (_Float16*)((char*)d_ws + qB);
    float*    part = (float*)((char*)d_ws + qB + fragB);

    mgsc_prep<<<(Mm * 16) / 256, 256, 0, stream>>>(y, yf, q, frag);
    mgsc_main<<<dim3(Nn / 128, NCH), 256, 0, stream>>>(x, q, frag, part);
    mgsc_reduce<<<(Nn * 16) / 256, 256, 0, stream>>>(part, out);
}